// Round 15
// baseline (87.129 us; speedup 1.0000x reference)
//
#include <hip/hip_runtime.h>
#include <hip/hip_bf16.h>
#include <stdint.h>

#define N_NODES 2048
#define FDIM 256

typedef short bf16x8 __attribute__((ext_vector_type(8)));   // 8 bf16 = 4 VGPRs (MFMA A/B frag)
typedef float f32x4 __attribute__((ext_vector_type(4)));
typedef unsigned short u16x4 __attribute__((ext_vector_type(4)));

static __device__ __forceinline__ unsigned short bf16r(float x) {
  __hip_bfloat16 h = __float2bfloat16(x);
  return __builtin_bit_cast(unsigned short, h);
}

// ---------------- k_prep: WT16 = bf16(W^T) [f][k]; wa1 = W@a1, wa2 = W@a2 (fp32) ---------------
__global__ __launch_bounds__(256) void k_prep(const float* __restrict__ W, const float* __restrict__ a,
                                              __hip_bfloat16* __restrict__ WT16,
                                              float* __restrict__ wa1, float* __restrict__ wa2) {
  int bid = blockIdx.x, t = threadIdx.x;
  if (bid < 16) {
    __shared__ __hip_bfloat16 T[64][67];
    int k0 = (bid & 3) * 64, f0 = (bid >> 2) * 64;
    int r = t >> 2, c0 = (t & 3) * 16;
    #pragma unroll
    for (int i = 0; i < 4; ++i) {
      f32x4 v = *(const f32x4*)(W + (size_t)(k0 + r) * FDIM + f0 + c0 + i * 4);
      #pragma unroll
      for (int j = 0; j < 4; ++j) T[r][c0 + i * 4 + j] = __float2bfloat16(v[j]);
    }
    __syncthreads();
    int fr = t >> 2, kc = (t & 3) * 16;
    unsigned short buf[16];
    #pragma unroll
    for (int i = 0; i < 16; ++i) buf[i] = __builtin_bit_cast(unsigned short, T[kc + i][fr]);
    uint4* dst = (uint4*)(WT16 + (size_t)(f0 + fr) * FDIM + k0 + kc);
    dst[0] = *(uint4*)&buf[0];
    dst[1] = *(uint4*)&buf[8];
  } else {
    int k = (bid - 16) * 64 + (t >> 2), q = t & 3;
    float s1 = 0.f, s2 = 0.f;
    #pragma unroll
    for (int i = 0; i < 16; ++i) {
      int f = q * 64 + i * 4;
      f32x4 w  = *(const f32x4*)(W + (size_t)k * FDIM + f);
      f32x4 v1 = *(const f32x4*)(a + f);
      f32x4 v2 = *(const f32x4*)(a + FDIM + f);
      #pragma unroll
      for (int j = 0; j < 4; ++j) { s1 += w[j] * v1[j]; s2 += w[j] * v2[j]; }
    }
    s1 += __shfl_xor(s1, 1); s1 += __shfl_xor(s1, 2);
    s2 += __shfl_xor(s2, 1); s2 += __shfl_xor(s2, 2);
    if (q == 0) { wa1[k] = s1; wa2[k] = s2; }
  }
}

// ---------------- k_h2p: adj-pack prologue + h = inp@W via MFMA -> Bf + e_src/e_dst ------------
// Bf[b][ft(16)][k0(64)][lane(64)][e(8)]: lane holds h[k = k0*32+(lane>>4)*8+e][f = ft*16+(lane&15)]
__global__ __launch_bounds__(256) void k_h2p(const float* __restrict__ inp,
                                             const int* __restrict__ adj, uint32_t* __restrict__ adjp,
                                             const __hip_bfloat16* __restrict__ WT16,
                                             const float* __restrict__ wa1, const float* __restrict__ wa2,
                                             __hip_bfloat16* __restrict__ Bf,
                                             float* __restrict__ e_src, float* __restrict__ e_dst) {
  __shared__ char lds_raw[20480];
  __hip_bfloat16* Asm = (__hip_bfloat16*)lds_raw;  // [32][264] bf16
  int t = threadIdx.x;
  int r0 = blockIdx.x * 32;
  int b = r0 >> 11, j0 = r0 & (N_NODES - 1);

  {  // ---- adj pack: rows bid*4 .. +4
    int prow = blockIdx.x * 4 + (t >> 6);
    int lane = t & 63;
    const int* row = adj + (size_t)prow * N_NODES;
    #pragma unroll
    for (int it = 0; it < 32; ++it) {
      int v = row[it * 64 + lane];
      unsigned long long m = __ballot(v != 0);
      if (lane == 0) {
        adjp[prow * 64 + it * 2]     = (uint32_t)(m & 0xffffffffull);
        adjp[prow * 64 + it * 2 + 1] = (uint32_t)(m >> 32);
      }
    }
  }

  {
    int r = t >> 3, q = t & 7, c0 = q * 32;
    const float* ip = inp + (size_t)(r0 + r) * FDIM + c0;
    float s1 = 0.f, s2 = 0.f;
    #pragma unroll
    for (int i = 0; i < 8; ++i) {
      f32x4 v  = *(const f32x4*)(ip + i * 4);
      f32x4 u1 = *(const f32x4*)(wa1 + c0 + i * 4);
      f32x4 u2 = *(const f32x4*)(wa2 + c0 + i * 4);
      u16x4 pk;
      #pragma unroll
      for (int j = 0; j < 4; ++j) {
        s1 += v[j] * u1[j];
        s2 += v[j] * u2[j];
        pk[j] = bf16r(v[j]);
      }
      *(u16x4*)(Asm + r * 264 + c0 + i * 4) = pk;
    }
    s1 += __shfl_xor(s1, 1); s1 += __shfl_xor(s1, 2); s1 += __shfl_xor(s1, 4);
    s2 += __shfl_xor(s2, 1); s2 += __shfl_xor(s2, 2); s2 += __shfl_xor(s2, 4);
    if (q == 0) { e_src[r0 + r] = s1; e_dst[r0 + r] = s2; }
  }
  __syncthreads();

  int lane = t & 63, wv = t >> 6, l15 = lane & 15, lq = lane >> 4;
  int f0 = wv * 64;
  f32x4 acc[2][4];
  #pragma unroll
  for (int mf = 0; mf < 2; ++mf)
    #pragma unroll
    for (int nf = 0; nf < 4; ++nf)
      #pragma unroll
      for (int e = 0; e < 4; ++e) acc[mf][nf][e] = 0.f;

  #pragma unroll
  for (int ks = 0; ks < 8; ++ks) {
    int k0 = ks * 32;
    bf16x8 af[2], bfr[4];
    #pragma unroll
    for (int mf = 0; mf < 2; ++mf)
      af[mf] = *(const bf16x8*)(Asm + (mf * 16 + l15) * 264 + k0 + lq * 8);
    #pragma unroll
    for (int nf = 0; nf < 4; ++nf)
      bfr[nf] = *(const bf16x8*)(WT16 + (size_t)(f0 + nf * 16 + l15) * FDIM + k0 + lq * 8);
    #pragma unroll
    for (int mf = 0; mf < 2; ++mf)
      #pragma unroll
      for (int nf = 0; nf < 4; ++nf)
        acc[mf][nf] = __builtin_amdgcn_mfma_f32_16x16x32_bf16(af[mf], bfr[nf], acc[mf][nf], 0, 0, 0);
  }

  __syncthreads();
  __hip_bfloat16* Tsm = (__hip_bfloat16*)lds_raw;  // [256][40] bf16: Tsm[f][j_local]
  #pragma unroll
  for (int mf = 0; mf < 2; ++mf)
    #pragma unroll
    for (int nf = 0; nf < 4; ++nf) {
      u16x4 pk;
      #pragma unroll
      for (int r = 0; r < 4; ++r) pk[r] = bf16r(acc[mf][nf][r]);
      int fl = f0 + nf * 16 + l15;
      int jl = mf * 16 + lq * 4;
      *(u16x4*)(Tsm + fl * 40 + jl) = pk;
    }
  __syncthreads();
  {
    int kt = j0 >> 5;                    // this block covers exactly one k0-block
    #pragma unroll
    for (int q = 0; q < 4; ++q) {
      int ft = (t >> 6) * 4 + q;
      uint4 v = *(const uint4*)(Tsm + (ft * 16 + l15) * 40 + lq * 8);
      *(uint4*)(Bf + ((((size_t)b * 16 + ft) * 64 + kt) * 64 + lane) * 8) = v;
    }
  }
}

// ---------------- k_ml: per (b,i) row: m = max_j masked-e, il = 1/sum exp(e-m) -----------------
__global__ __launch_bounds__(256) void k_ml(const uint32_t* __restrict__ adjp,
                                            const float* __restrict__ e_src,
                                            const float* __restrict__ e_dst,
                                            float* __restrict__ mrow, float* __restrict__ ilrow) {
  int t = threadIdx.x;
  int lane = t & 63;
  int r = blockIdx.x * 4 + (t >> 6);
  int b = r >> 11, i = r & (N_NODES - 1);
  float es = e_src[r];
  const float* edb = e_dst + ((size_t)b << 11);
  const uint32_t* arow = adjp + (size_t)i * 64;
  float ev[32];
  float mx = -3e38f;
  #pragma unroll
  for (int it = 0; it < 32; ++it) {
    int j = it * 64 + lane;
    float ed = edb[j];
    uint32_t w = arow[j >> 5];
    float s = es + ed;
    float lr = fmaxf(s, 0.01f * s);
    float e = ((w >> (j & 31)) & 1u) ? lr : -1e9f;
    ev[it] = e;
    mx = fmaxf(mx, e);
  }
  #pragma unroll
  for (int m = 1; m <= 32; m <<= 1) mx = fmaxf(mx, __shfl_xor(mx, m));
  float sum = 0.f;
  #pragma unroll
  for (int it = 0; it < 32; ++it) sum += __expf(ev[it] - mx);
  #pragma unroll
  for (int m = 1; m <= 32; m <<= 1) sum += __shfl_xor(sum, m);
  if (lane == 0) { mrow[r] = mx; ilrow[r] = 1.0f / sum; }
}

// ---------------- k_pvF5: out = relu(P @ H); 32i x 128f blocks, grid 1024, 4 blocks/CU ---------
// grid: b = bid&7 (XCD-pinned), it = (bid>>3)&63 (32 rows), fh = bid>>9 (128 f-cols).
// 4 waves; wave wv (sub=wv&1, par=wv>>1) produces 2 A-frags per 4-k0 chunk into dbuf LDS;
// consumes 2 A-frags x 2 B-frags (ft = fh*8 + wv*2 + n) -> 4 MFMA per k0. 1 barrier per chunk.
// LDS: Abuf 16KB + sm_ed 8KB + sm_adj 8.3KB = 32.1KB -> 4 blocks/CU.
__global__ __launch_bounds__(256) void k_pvF5(const __hip_bfloat16* __restrict__ Bf,
                                              const uint32_t* __restrict__ adjp,
                                              const float* __restrict__ e_src,
                                              const float* __restrict__ e_dst,
                                              const float* __restrict__ mrow,
                                              const float* __restrict__ ilrow,
                                              float* __restrict__ out) {
  __shared__ __align__(16) char Abuf[16384];   // [2 buf][4 k0l][2 sub][64 lane][16B]
  __shared__ float sm_ed[2048];                // 8 KB
  __shared__ uint32_t sm_adj[32 * 65];         // 8.3 KB
  int t = threadIdx.x;
  int b  = blockIdx.x & 7;
  int it = (blockIdx.x >> 3) & 63;
  int fh = blockIdx.x >> 9;
  int i0 = it * 32;
  int lane = t & 63, wv = t >> 6, l15 = lane & 15, lq = lane >> 4;
  int sub = wv & 1, par = wv >> 1;

  {  // stage e_dst row (2048 f32): 256 thr x 8 floats
    f32x4 v0 = *(const f32x4*)(e_dst + ((size_t)b << 11) + t * 8);
    f32x4 v1 = *(const f32x4*)(e_dst + ((size_t)b << 11) + t * 8 + 4);
    *(f32x4*)(sm_ed + t * 8) = v0;
    *(f32x4*)(sm_ed + t * 8 + 4) = v1;
  }
  {  // stage adjp rows i0..i0+32: 256 thr x 8 words
    int row = t >> 3, q = t & 7;
    const uint4* s = (const uint4*)(adjp + (size_t)(i0 + row) * 64 + q * 8);
    uint32_t* d = sm_adj + row * 65 + q * 8;
    uint4 v0 = s[0], v1 = s[1];
    *(uint4*)(d) = v0; *(uint4*)(d + 4) = v1;
  }
  // per-lane row constants for the frag rows this wave produces (rows sub*16 + l15)
  int fr_row = sub * 16 + l15;
  int rg = (b << 11) + i0 + fr_row;
  float es = e_src[rg], mi = mrow[rg], ili = ilrow[rg];
  int adjbase = fr_row * 65;
  int edoff = lq * 8;
  __syncthreads();

  auto computeA = [&](int k0) -> uint4 {
    uint32_t w = sm_adj[adjbase + k0] >> (lq * 8);
    f32x4 e0 = *(const f32x4*)(sm_ed + k0 * 32 + edoff);
    f32x4 e1 = *(const f32x4*)(sm_ed + k0 * 32 + edoff + 4);
    unsigned short u[8];
    #pragma unroll
    for (int e = 0; e < 8; ++e) {
      float ed = (e < 4) ? e0[e] : e1[e - 4];
      float s = es + ed;
      float lr = fmaxf(s, 0.01f * s);
      float p = __expf(lr - mi) * ili;       // R10-proven math
      p = ((w >> e) & 1u) ? p : 0.0f;        // masked: exact 0
      u[e] = bf16r(p);
    }
    uint4 v;
    v.x = (uint32_t)u[0] | ((uint32_t)u[1] << 16);
    v.y = (uint32_t)u[2] | ((uint32_t)u[3] << 16);
    v.z = (uint32_t)u[4] | ((uint32_t)u[5] << 16);
    v.w = (uint32_t)u[6] | ((uint32_t)u[7] << 16);
    return v;
  };

  auto produce = [&](int buf, int ch) {
    #pragma unroll
    for (int q = 0; q < 2; ++q) {
      int k0l = q * 2 + par;
      uint4 fr = computeA(ch * 4 + k0l);
      *(uint4*)(Abuf + (((buf * 4 + k0l) * 2 + sub) << 10) + lane * 16) = fr;
    }
  };

  // B pointers: ft = fh*8 + wv*2 + n
  const __hip_bfloat16* Bp0 = Bf + (((size_t)b * 16 + fh * 8 + wv * 2)     * 64) * 512 + (size_t)lane * 8;
  const __hip_bfloat16* Bp1 = Bf + (((size_t)b * 16 + fh * 8 + wv * 2 + 1) * 64) * 512 + (size_t)lane * 8;

  f32x4 acc[2][2];
  #pragma unroll
  for (int m = 0; m < 2; ++m)
    #pragma unroll
    for (int n = 0; n < 2; ++n)
      #pragma unroll
      for (int e = 0; e < 4; ++e) acc[m][n][e] = 0.f;

  bf16x8 bA0 = *(const bf16x8*)(Bp0);            // even k0
  bf16x8 bA1 = *(const bf16x8*)(Bp1);
  bf16x8 bB0 = *(const bf16x8*)(Bp0 + 512);      // odd k0
  bf16x8 bB1 = *(const bf16x8*)(Bp1 + 512);

  produce(0, 0);
  __syncthreads();

  for (int ch = 0; ch < 16; ++ch) {
    int buf = ch & 1;
    if (ch < 15) produce(buf ^ 1, ch + 1);
    const char* Ab = Abuf + buf * 8192;
    #pragma unroll
    for (int k0l = 0; k0l < 4; ++k0l) {
      int k0 = ch * 4 + k0l;
      bf16x8 af[2];
      #pragma unroll
      for (int m = 0; m < 2; ++m)
        af[m] = *(const bf16x8*)(Ab + ((k0l * 2 + m) << 10) + lane * 16);
      bf16x8 cb0 = (k0l & 1) ? bB0 : bA0;
      bf16x8 cb1 = (k0l & 1) ? bB1 : bA1;
      if (k0 + 2 < 64) {
        if (k0l & 1) { bB0 = *(const bf16x8*)(Bp0 + (size_t)(k0 + 2) * 512); bB1 = *(const bf16x8*)(Bp1 + (size_t)(k0 + 2) * 512); }
        else         { bA0 = *(const bf16x8*)(Bp0 + (size_t)(k0 + 2) * 512); bA1 = *(const bf16x8*)(Bp1 + (size_t)(k0 + 2) * 512); }
      }
      #pragma unroll
      for (int m = 0; m < 2; ++m) {
        acc[m][0] = __builtin_amdgcn_mfma_f32_16x16x32_bf16(af[m], cb0, acc[m][0], 0, 0, 0);
        acc[m][1] = __builtin_amdgcn_mfma_f32_16x16x32_bf16(af[m], cb1, acc[m][1], 0, 0, 0);
      }
    }
    __syncthreads();
  }

  #pragma unroll
  for (int m = 0; m < 2; ++m)
    #pragma unroll
    for (int n = 0; n < 2; ++n) {
      int col = (fh * 8 + wv * 2 + n) * 16 + l15;
      int orow = (b << 11) + i0 + m * 16 + lq * 4;
      #pragma unroll
      for (int r = 0; r < 4; ++r)
        out[(size_t)(orow + r) * FDIM + col] = fmaxf(acc[m][n][r], 0.0f);
    }
}

extern "C" void kernel_launch(void* const* d_in, const int* in_sizes, int n_in,
                              void* d_out, int out_size, void* d_ws, size_t ws_size,
                              hipStream_t stream) {
  const float* inp = (const float*)d_in[0];
  const int*   adj = (const int*)d_in[1];
  const float* W   = (const float*)d_in[2];
  const float* a   = (const float*)d_in[3];
  float* out = (float*)d_out;
  char* ws = (char*)d_ws;

  __hip_bfloat16* Bf   = (__hip_bfloat16*)ws;              //  8,388,608
  float* e_src         = (float*)(ws + 8388608);           //     65,536
  float* e_dst         = (float*)(ws + 8454144);           //     65,536
  float* mrow          = (float*)(ws + 8519680);           //     65,536
  float* ilrow         = (float*)(ws + 8585216);           //     65,536
  __hip_bfloat16* WT16 = (__hip_bfloat16*)(ws + 8650752);  //    131,072
  float* wa1           = (float*)(ws + 8781824);           //      1,024
  float* wa2           = (float*)(ws + 8782848);           //      1,024
  uint32_t* adjp       = (uint32_t*)(ws + 8783872);        //    524,288 -> end 9,308,160

  k_prep<<<20, 256, 0, stream>>>(W, a, WT16, wa1, wa2);
  k_h2p<<<512, 256, 0, stream>>>(inp, adj, adjp, WT16, wa1, wa2, Bf, e_src, e_dst);
  k_ml<<<4096, 256, 0, stream>>>(adjp, e_src, e_dst, mrow, ilrow);
  k_pvF5<<<1024, 256, 0, stream>>>(Bf, adjp, e_src, e_dst, mrow, ilrow, out);
}

// Round 16
// 79.450 us; speedup vs baseline: 1.0967x; 1.0967x over previous
//
#include <hip/hip_runtime.h>
#include <hip/hip_bf16.h>
#include <stdint.h>

#define N_NODES 2048
#define FDIM 256
#define LOG2E 1.44269504088896340736f

typedef short bf16x8 __attribute__((ext_vector_type(8)));   // 8 bf16 = 4 VGPRs (MFMA A/B frag)
typedef float f32x4 __attribute__((ext_vector_type(4)));
typedef unsigned short u16x4 __attribute__((ext_vector_type(4)));

static __device__ __forceinline__ unsigned short bf16r(float x) {
  __hip_bfloat16 h = __float2bfloat16(x);
  return __builtin_bit_cast(unsigned short, h);
}

static __device__ __forceinline__ float exp2_hw(float x) { return __builtin_amdgcn_exp2f(x); }
static __device__ __forceinline__ float log2_hw(float x) { return __builtin_amdgcn_logf(x); }

// ---------------- k_prep: WT16 = bf16(W^T); wa1/wa2 = (W@a1/2) * log2(e) --------------------
// wa scaling puts e_src/e_dst in the log2 domain; h path (WT16) is UNscaled.
__global__ __launch_bounds__(256) void k_prep(const float* __restrict__ W, const float* __restrict__ a,
                                              __hip_bfloat16* __restrict__ WT16,
                                              float* __restrict__ wa1, float* __restrict__ wa2) {
  int bid = blockIdx.x, t = threadIdx.x;
  if (bid < 16) {
    __shared__ __hip_bfloat16 T[64][67];
    int k0 = (bid & 3) * 64, f0 = (bid >> 2) * 64;
    int r = t >> 2, c0 = (t & 3) * 16;
    #pragma unroll
    for (int i = 0; i < 4; ++i) {
      f32x4 v = *(const f32x4*)(W + (size_t)(k0 + r) * FDIM + f0 + c0 + i * 4);
      #pragma unroll
      for (int j = 0; j < 4; ++j) T[r][c0 + i * 4 + j] = __float2bfloat16(v[j]);
    }
    __syncthreads();
    int fr = t >> 2, kc = (t & 3) * 16;
    unsigned short buf[16];
    #pragma unroll
    for (int i = 0; i < 16; ++i) buf[i] = __builtin_bit_cast(unsigned short, T[kc + i][fr]);
    uint4* dst = (uint4*)(WT16 + (size_t)(f0 + fr) * FDIM + k0 + kc);
    dst[0] = *(uint4*)&buf[0];
    dst[1] = *(uint4*)&buf[8];
  } else {
    int k = (bid - 16) * 64 + (t >> 2), q = t & 3;
    float s1 = 0.f, s2 = 0.f;
    #pragma unroll
    for (int i = 0; i < 16; ++i) {
      int f = q * 64 + i * 4;
      f32x4 w  = *(const f32x4*)(W + (size_t)k * FDIM + f);
      f32x4 v1 = *(const f32x4*)(a + f);
      f32x4 v2 = *(const f32x4*)(a + FDIM + f);
      #pragma unroll
      for (int j = 0; j < 4; ++j) { s1 += w[j] * v1[j]; s2 += w[j] * v2[j]; }
    }
    s1 += __shfl_xor(s1, 1); s1 += __shfl_xor(s1, 2);
    s2 += __shfl_xor(s2, 1); s2 += __shfl_xor(s2, 2);
    if (q == 0) { wa1[k] = s1 * LOG2E; wa2[k] = s2 * LOG2E; }
  }
}

// ---------------- k_h2p: adj-pack prologue + h = inp@W via MFMA -> Bf + e_src/e_dst ------------
// Bf[b][ft(16)][k0(64)][lane(64)][e(8)]: lane holds h[k = k0*32+(lane>>4)*8+e][f = ft*16+(lane&15)]
__global__ __launch_bounds__(256) void k_h2p(const float* __restrict__ inp,
                                             const int* __restrict__ adj, uint32_t* __restrict__ adjp,
                                             const __hip_bfloat16* __restrict__ WT16,
                                             const float* __restrict__ wa1, const float* __restrict__ wa2,
                                             __hip_bfloat16* __restrict__ Bf,
                                             float* __restrict__ e_src, float* __restrict__ e_dst) {
  __shared__ char lds_raw[20480];
  __hip_bfloat16* Asm = (__hip_bfloat16*)lds_raw;  // [32][264] bf16
  int t = threadIdx.x;
  int r0 = blockIdx.x * 32;
  int b = r0 >> 11, j0 = r0 & (N_NODES - 1);

  {  // ---- adj pack: rows bid*4 .. +4
    int prow = blockIdx.x * 4 + (t >> 6);
    int lane = t & 63;
    const int* row = adj + (size_t)prow * N_NODES;
    #pragma unroll
    for (int it = 0; it < 32; ++it) {
      int v = row[it * 64 + lane];
      unsigned long long m = __ballot(v != 0);
      if (lane == 0) {
        adjp[prow * 64 + it * 2]     = (uint32_t)(m & 0xffffffffull);
        adjp[prow * 64 + it * 2 + 1] = (uint32_t)(m >> 32);
      }
    }
  }

  {
    int r = t >> 3, q = t & 7, c0 = q * 32;
    const float* ip = inp + (size_t)(r0 + r) * FDIM + c0;
    float s1 = 0.f, s2 = 0.f;
    #pragma unroll
    for (int i = 0; i < 8; ++i) {
      f32x4 v  = *(const f32x4*)(ip + i * 4);
      f32x4 u1 = *(const f32x4*)(wa1 + c0 + i * 4);
      f32x4 u2 = *(const f32x4*)(wa2 + c0 + i * 4);
      u16x4 pk;
      #pragma unroll
      for (int j = 0; j < 4; ++j) {
        s1 += v[j] * u1[j];
        s2 += v[j] * u2[j];
        pk[j] = bf16r(v[j]);
      }
      *(u16x4*)(Asm + r * 264 + c0 + i * 4) = pk;
    }
    s1 += __shfl_xor(s1, 1); s1 += __shfl_xor(s1, 2); s1 += __shfl_xor(s1, 4);
    s2 += __shfl_xor(s2, 1); s2 += __shfl_xor(s2, 2); s2 += __shfl_xor(s2, 4);
    if (q == 0) { e_src[r0 + r] = s1; e_dst[r0 + r] = s2; }
  }
  __syncthreads();

  int lane = t & 63, wv = t >> 6, l15 = lane & 15, lq = lane >> 4;
  int f0 = wv * 64;
  f32x4 acc[2][4];
  #pragma unroll
  for (int mf = 0; mf < 2; ++mf)
    #pragma unroll
    for (int nf = 0; nf < 4; ++nf)
      #pragma unroll
      for (int e = 0; e < 4; ++e) acc[mf][nf][e] = 0.f;

  #pragma unroll
  for (int ks = 0; ks < 8; ++ks) {
    int k0 = ks * 32;
    bf16x8 af[2], bfr[4];
    #pragma unroll
    for (int mf = 0; mf < 2; ++mf)
      af[mf] = *(const bf16x8*)(Asm + (mf * 16 + l15) * 264 + k0 + lq * 8);
    #pragma unroll
    for (int nf = 0; nf < 4; ++nf)
      bfr[nf] = *(const bf16x8*)(WT16 + (size_t)(f0 + nf * 16 + l15) * FDIM + k0 + lq * 8);
    #pragma unroll
    for (int mf = 0; mf < 2; ++mf)
      #pragma unroll
      for (int nf = 0; nf < 4; ++nf)
        acc[mf][nf] = __builtin_amdgcn_mfma_f32_16x16x32_bf16(af[mf], bfr[nf], acc[mf][nf], 0, 0, 0);
  }

  __syncthreads();
  __hip_bfloat16* Tsm = (__hip_bfloat16*)lds_raw;  // [256][40] bf16: Tsm[f][j_local]
  #pragma unroll
  for (int mf = 0; mf < 2; ++mf)
    #pragma unroll
    for (int nf = 0; nf < 4; ++nf) {
      u16x4 pk;
      #pragma unroll
      for (int r = 0; r < 4; ++r) pk[r] = bf16r(acc[mf][nf][r]);
      int fl = f0 + nf * 16 + l15;
      int jl = mf * 16 + lq * 4;
      *(u16x4*)(Tsm + fl * 40 + jl) = pk;
    }
  __syncthreads();
  {
    int kt = j0 >> 5;                    // this block covers exactly one k0-block
    #pragma unroll
    for (int q = 0; q < 4; ++q) {
      int ft = (t >> 6) * 4 + q;
      uint4 v = *(const uint4*)(Tsm + (ft * 16 + l15) * 40 + lq * 8);
      *(uint4*)(Bf + ((((size_t)b * 16 + ft) * 64 + kt) * 64 + lane) * 8) = v;
    }
  }
}

// ---------------- k_lse: per (b,i) row: lse = mx + log2(sum 2^(e-mx)); e in log2 domain --------
__global__ __launch_bounds__(256) void k_lse(const uint32_t* __restrict__ adjp,
                                             const float* __restrict__ e_src,
                                             const float* __restrict__ e_dst,
                                             float* __restrict__ lserow) {
  int t = threadIdx.x;
  int lane = t & 63;
  int r = blockIdx.x * 4 + (t >> 6);
  int b = r >> 11, i = r & (N_NODES - 1);
  float es = e_src[r];
  const float* edb = e_dst + ((size_t)b << 11);
  const uint32_t* arow = adjp + (size_t)i * 64;
  float ev[32];
  float mx = -3e38f;
  #pragma unroll
  for (int it = 0; it < 32; ++it) {
    int j = it * 64 + lane;
    float ed = edb[j];
    uint32_t w = arow[j >> 5];
    float s = es + ed;
    float lr = fmaxf(s, 0.01f * s);
    float e = ((w >> (j & 31)) & 1u) ? lr : -1e9f;
    ev[it] = e;
    mx = fmaxf(mx, e);
  }
  #pragma unroll
  for (int m = 1; m <= 32; m <<= 1) mx = fmaxf(mx, __shfl_xor(mx, m));
  float sum = 0.f;
  #pragma unroll
  for (int it = 0; it < 32; ++it) sum += exp2_hw(ev[it] - mx);
  #pragma unroll
  for (int m = 1; m <= 32; m <<= 1) sum += __shfl_xor(sum, m);
  if (lane == 0) lserow[r] = mx + log2_hw(sum);
}

// ---------------- k_pvF3L: out = relu(P @ H); R=1 shared A-frags, log2-domain P ---------------
// Identical structure to R13's k_pvF3 (LDS 57.3KB < 64KB). computeA: p = 2^(lr_l2 - lse).
__global__ __launch_bounds__(512) void k_pvF3L(const __hip_bfloat16* __restrict__ Bf,
                                               const uint32_t* __restrict__ adjp,
                                               const float* __restrict__ e_src,
                                               const float* __restrict__ e_dst,
                                               const float* __restrict__ lserow,
                                               float* __restrict__ out) {
  __shared__ __align__(16) char Abuf[32768];   // [2 buf][4 k0l][4 sub][64 lane][16B]
  __shared__ float sm_ed[2048];                // 8 KB
  __shared__ uint32_t sm_adj[64 * 65];         // 16.6 KB
  int t = threadIdx.x;
  int b  = blockIdx.x & 7;
  int it = blockIdx.x >> 3;
  int i0 = it * 64;
  int lane = t & 63, wv = t >> 6, l15 = lane & 15, lq = lane >> 4;
  int sub = wv & 3, par = wv >> 2;

  *(f32x4*)(sm_ed + t * 4) = *(const f32x4*)(e_dst + ((size_t)b << 11) + t * 4);
  {
    int row = t >> 3, q = t & 7;
    const uint4* s = (const uint4*)(adjp + (size_t)(i0 + row) * 64 + q * 8);
    uint32_t* d = sm_adj + row * 65 + q * 8;
    uint4 v0 = s[0], v1 = s[1];
    *(uint4*)(d) = v0; *(uint4*)(d + 4) = v1;
  }
  // per-lane row constants for the frag rows this wave produces (rows sub*16 + l15)
  int rg = (b << 11) + i0 + sub * 16 + l15;
  float es = e_src[rg], lse = lserow[rg];
  float esl = es - lse;                 // s_l2 - lse = esl + ed
  float c2  = fmaf(0.01f, es, -lse);    // 0.01*s_l2 - lse = fma(0.01, ed, c2)
  int adjbase = (sub * 16 + l15) * 65;
  int edoff = lq * 8;
  __syncthreads();

  auto computeA = [&](int k0) -> uint4 {
    uint32_t w = sm_adj[adjbase + k0] >> (lq * 8);
    f32x4 e0 = *(const f32x4*)(sm_ed + k0 * 32 + edoff);
    f32x4 e1 = *(const f32x4*)(sm_ed + k0 * 32 + edoff + 4);
    unsigned short u[8];
    #pragma unroll
    for (int e = 0; e < 8; ++e) {
      float ed = (e < 4) ? e0[e] : e1[e - 4];
      float v = fmaxf(esl + ed, fmaf(0.01f, ed, c2));
      float p = exp2_hw(v);
      p = ((w >> e) & 1u) ? p : 0.0f;        // masked: exact 0
      u[e] = bf16r(p);
    }
    uint4 v;
    v.x = (uint32_t)u[0] | ((uint32_t)u[1] << 16);
    v.y = (uint32_t)u[2] | ((uint32_t)u[3] << 16);
    v.z = (uint32_t)u[4] | ((uint32_t)u[5] << 16);
    v.w = (uint32_t)u[6] | ((uint32_t)u[7] << 16);
    return v;
  };

  auto produce = [&](int buf, int ch) {
    #pragma unroll
    for (int q = 0; q < 2; ++q) {
      int k0l = q * 2 + par;
      uint4 fr = computeA(ch * 4 + k0l);
      *(uint4*)(Abuf + (((buf * 4 + k0l) * 4 + sub) << 10) + lane * 16) = fr;
    }
  };

  // B pointers: ft = wv*2 + n
  const __hip_bfloat16* Bp0 = Bf + (((size_t)b * 16 + wv * 2)     * 64) * 512 + (size_t)lane * 8;
  const __hip_bfloat16* Bp1 = Bf + (((size_t)b * 16 + wv * 2 + 1) * 64) * 512 + (size_t)lane * 8;

  f32x4 acc[4][2];
  #pragma unroll
  for (int m = 0; m < 4; ++m)
    #pragma unroll
    for (int n = 0; n < 2; ++n)
      #pragma unroll
      for (int e = 0; e < 4; ++e) acc[m][n][e] = 0.f;

  bf16x8 bA0 = *(const bf16x8*)(Bp0);            // even k0
  bf16x8 bA1 = *(const bf16x8*)(Bp1);
  bf16x8 bB0 = *(const bf16x8*)(Bp0 + 512);      // odd k0
  bf16x8 bB1 = *(const bf16x8*)(Bp1 + 512);

  produce(0, 0);
  __syncthreads();

  for (int ch = 0; ch < 16; ++ch) {
    int buf = ch & 1;
    if (ch < 15) produce(buf ^ 1, ch + 1);
    const char* Ab = Abuf + buf * 16384;
    #pragma unroll
    for (int k0l = 0; k0l < 4; ++k0l) {
      int k0 = ch * 4 + k0l;
      bf16x8 af[4];
      #pragma unroll
      for (int m = 0; m < 4; ++m)
        af[m] = *(const bf16x8*)(Ab + ((k0l * 4 + m) << 10) + lane * 16);
      bf16x8 cb0 = (k0l & 1) ? bB0 : bA0;
      bf16x8 cb1 = (k0l & 1) ? bB1 : bA1;
      if (k0 + 2 < 64) {
        if (k0l & 1) { bB0 = *(const bf16x8*)(Bp0 + (size_t)(k0 + 2) * 512); bB1 = *(const bf16x8*)(Bp1 + (size_t)(k0 + 2) * 512); }
        else         { bA0 = *(const bf16x8*)(Bp0 + (size_t)(k0 + 2) * 512); bA1 = *(const bf16x8*)(Bp1 + (size_t)(k0 + 2) * 512); }
      }
      #pragma unroll
      for (int m = 0; m < 4; ++m) {
        acc[m][0] = __builtin_amdgcn_mfma_f32_16x16x32_bf16(af[m], cb0, acc[m][0], 0, 0, 0);
        acc[m][1] = __builtin_amdgcn_mfma_f32_16x16x32_bf16(af[m], cb1, acc[m][1], 0, 0, 0);
      }
    }
    __syncthreads();
  }

  #pragma unroll
  for (int m = 0; m < 4; ++m)
    #pragma unroll
    for (int n = 0; n < 2; ++n) {
      int col = (wv * 2 + n) * 16 + l15;
      int orow = (b << 11) + i0 + m * 16 + lq * 4;
      #pragma unroll
      for (int r = 0; r < 4; ++r)
        out[(size_t)(orow + r) * FDIM + col] = fmaxf(acc[m][n][r], 0.0f);
    }
}

extern "C" void kernel_launch(void* const* d_in, const int* in_sizes, int n_in,
                              void* d_out, int out_size, void* d_ws, size_t ws_size,
                              hipStream_t stream) {
  const float* inp = (const float*)d_in[0];
  const int*   adj = (const int*)d_in[1];
  const float* W   = (const float*)d_in[2];
  const float* a   = (const float*)d_in[3];
  float* out = (float*)d_out;
  char* ws = (char*)d_ws;

  __hip_bfloat16* Bf   = (__hip_bfloat16*)ws;              //  8,388,608
  float* e_src         = (float*)(ws + 8388608);           //     65,536
  float* e_dst         = (float*)(ws + 8454144);           //     65,536
  float* lserow        = (float*)(ws + 8519680);           //     65,536
  __hip_bfloat16* WT16 = (__hip_bfloat16*)(ws + 8585216);  //    131,072
  float* wa1           = (float*)(ws + 8716288);           //      1,024
  float* wa2           = (float*)(ws + 8717312);           //      1,024
  uint32_t* adjp       = (uint32_t*)(ws + 8718336);        //    524,288 -> end 9,242,624

  k_prep<<<20, 256, 0, stream>>>(W, a, WT16, wa1, wa2);
  k_h2p<<<512, 256, 0, stream>>>(inp, adj, adjp, WT16, wa1, wa2, Bf, e_src, e_dst);
  k_lse<<<4096, 256, 0, stream>>>(adjp, e_src, e_dst, lserow);
  k_pvF3L<<<256, 512, 0, stream>>>(Bf, adjp, e_src, e_dst, lserow, out);
}

// Round 17
// 76.307 us; speedup vs baseline: 1.1418x; 1.0412x over previous
//
#include <hip/hip_runtime.h>
#include <hip/hip_bf16.h>
#include <stdint.h>

#define N_NODES 2048
#define FDIM 256
#define LOG2E 1.44269504088896340736f

typedef short bf16x8 __attribute__((ext_vector_type(8)));   // 8 bf16 = 4 VGPRs (MFMA A/B frag)
typedef float f32x4 __attribute__((ext_vector_type(4)));
typedef unsigned short u16x4 __attribute__((ext_vector_type(4)));

static __device__ __forceinline__ unsigned short bf16r(float x) {
  __hip_bfloat16 h = __float2bfloat16(x);
  return __builtin_bit_cast(unsigned short, h);
}

static __device__ __forceinline__ float exp2_hw(float x) { return __builtin_amdgcn_exp2f(x); }
static __device__ __forceinline__ float log2_hw(float x) { return __builtin_amdgcn_logf(x); }

// ---------------- k_prep: WT16 = bf16(W^T); wa1/wa2 = (W@a1/2) * log2(e) --------------------
__global__ __launch_bounds__(256) void k_prep(const float* __restrict__ W, const float* __restrict__ a,
                                              __hip_bfloat16* __restrict__ WT16,
                                              float* __restrict__ wa1, float* __restrict__ wa2) {
  int bid = blockIdx.x, t = threadIdx.x;
  if (bid < 16) {
    __shared__ __hip_bfloat16 T[64][67];
    int k0 = (bid & 3) * 64, f0 = (bid >> 2) * 64;
    int r = t >> 2, c0 = (t & 3) * 16;
    #pragma unroll
    for (int i = 0; i < 4; ++i) {
      f32x4 v = *(const f32x4*)(W + (size_t)(k0 + r) * FDIM + f0 + c0 + i * 4);
      #pragma unroll
      for (int j = 0; j < 4; ++j) T[r][c0 + i * 4 + j] = __float2bfloat16(v[j]);
    }
    __syncthreads();
    int fr = t >> 2, kc = (t & 3) * 16;
    unsigned short buf[16];
    #pragma unroll
    for (int i = 0; i < 16; ++i) buf[i] = __builtin_bit_cast(unsigned short, T[kc + i][fr]);
    uint4* dst = (uint4*)(WT16 + (size_t)(f0 + fr) * FDIM + k0 + kc);
    dst[0] = *(uint4*)&buf[0];
    dst[1] = *(uint4*)&buf[8];
  } else {
    int k = (bid - 16) * 64 + (t >> 2), q = t & 3;
    float s1 = 0.f, s2 = 0.f;
    #pragma unroll
    for (int i = 0; i < 16; ++i) {
      int f = q * 64 + i * 4;
      f32x4 w  = *(const f32x4*)(W + (size_t)k * FDIM + f);
      f32x4 v1 = *(const f32x4*)(a + f);
      f32x4 v2 = *(const f32x4*)(a + FDIM + f);
      #pragma unroll
      for (int j = 0; j < 4; ++j) { s1 += w[j] * v1[j]; s2 += w[j] * v2[j]; }
    }
    s1 += __shfl_xor(s1, 1); s1 += __shfl_xor(s1, 2);
    s2 += __shfl_xor(s2, 1); s2 += __shfl_xor(s2, 2);
    if (q == 0) { wa1[k] = s1 * LOG2E; wa2[k] = s2 * LOG2E; }
  }
}

// ---------------- k_h2p: adj-pack prologue + h = inp@W via MFMA -> Bf + e_src/e_dst ------------
// Bf[b][ft(16)][k0(64)][lane(64)][e(8)]: lane holds h[k = k0*32+(lane>>4)*8+e][f = ft*16+(lane&15)]
__global__ __launch_bounds__(256) void k_h2p(const float* __restrict__ inp,
                                             const int* __restrict__ adj, uint32_t* __restrict__ adjp,
                                             const __hip_bfloat16* __restrict__ WT16,
                                             const float* __restrict__ wa1, const float* __restrict__ wa2,
                                             __hip_bfloat16* __restrict__ Bf,
                                             float* __restrict__ e_src, float* __restrict__ e_dst) {
  __shared__ char lds_raw[20480];
  __hip_bfloat16* Asm = (__hip_bfloat16*)lds_raw;  // [32][264] bf16
  int t = threadIdx.x;
  int r0 = blockIdx.x * 32;
  int b = r0 >> 11, j0 = r0 & (N_NODES - 1);

  {  // ---- adj pack: rows bid*4 .. +4
    int prow = blockIdx.x * 4 + (t >> 6);
    int lane = t & 63;
    const int* row = adj + (size_t)prow * N_NODES;
    #pragma unroll
    for (int it = 0; it < 32; ++it) {
      int v = row[it * 64 + lane];
      unsigned long long m = __ballot(v != 0);
      if (lane == 0) {
        adjp[prow * 64 + it * 2]     = (uint32_t)(m & 0xffffffffull);
        adjp[prow * 64 + it * 2 + 1] = (uint32_t)(m >> 32);
      }
    }
  }

  {
    int r = t >> 3, q = t & 7, c0 = q * 32;
    const float* ip = inp + (size_t)(r0 + r) * FDIM + c0;
    float s1 = 0.f, s2 = 0.f;
    #pragma unroll
    for (int i = 0; i < 8; ++i) {
      f32x4 v  = *(const f32x4*)(ip + i * 4);
      f32x4 u1 = *(const f32x4*)(wa1 + c0 + i * 4);
      f32x4 u2 = *(const f32x4*)(wa2 + c0 + i * 4);
      u16x4 pk;
      #pragma unroll
      for (int j = 0; j < 4; ++j) {
        s1 += v[j] * u1[j];
        s2 += v[j] * u2[j];
        pk[j] = bf16r(v[j]);
      }
      *(u16x4*)(Asm + r * 264 + c0 + i * 4) = pk;
    }
    s1 += __shfl_xor(s1, 1); s1 += __shfl_xor(s1, 2); s1 += __shfl_xor(s1, 4);
    s2 += __shfl_xor(s2, 1); s2 += __shfl_xor(s2, 2); s2 += __shfl_xor(s2, 4);
    if (q == 0) { e_src[r0 + r] = s1; e_dst[r0 + r] = s2; }
  }
  __syncthreads();

  int lane = t & 63, wv = t >> 6, l15 = lane & 15, lq = lane >> 4;
  int f0 = wv * 64;
  f32x4 acc[2][4];
  #pragma unroll
  for (int mf = 0; mf < 2; ++mf)
    #pragma unroll
    for (int nf = 0; nf < 4; ++nf)
      #pragma unroll
      for (int e = 0; e < 4; ++e) acc[mf][nf][e] = 0.f;

  #pragma unroll
  for (int ks = 0; ks < 8; ++ks) {
    int k0 = ks * 32;
    bf16x8 af[2], bfr[4];
    #pragma unroll
    for (int mf = 0; mf < 2; ++mf)
      af[mf] = *(const bf16x8*)(Asm + (mf * 16 + l15) * 264 + k0 + lq * 8);
    #pragma unroll
    for (int nf = 0; nf < 4; ++nf)
      bfr[nf] = *(const bf16x8*)(WT16 + (size_t)(f0 + nf * 16 + l15) * FDIM + k0 + lq * 8);
    #pragma unroll
    for (int mf = 0; mf < 2; ++mf)
      #pragma unroll
      for (int nf = 0; nf < 4; ++nf)
        acc[mf][nf] = __builtin_amdgcn_mfma_f32_16x16x32_bf16(af[mf], bfr[nf], acc[mf][nf], 0, 0, 0);
  }

  __syncthreads();
  __hip_bfloat16* Tsm = (__hip_bfloat16*)lds_raw;  // [256][40] bf16: Tsm[f][j_local]
  #pragma unroll
  for (int mf = 0; mf < 2; ++mf)
    #pragma unroll
    for (int nf = 0; nf < 4; ++nf) {
      u16x4 pk;
      #pragma unroll
      for (int r = 0; r < 4; ++r) pk[r] = bf16r(acc[mf][nf][r]);
      int fl = f0 + nf * 16 + l15;
      int jl = mf * 16 + lq * 4;
      *(u16x4*)(Tsm + fl * 40 + jl) = pk;
    }
  __syncthreads();
  {
    int kt = j0 >> 5;                    // this block covers exactly one k0-block
    #pragma unroll
    for (int q = 0; q < 4; ++q) {
      int ft = (t >> 6) * 4 + q;
      uint4 v = *(const uint4*)(Tsm + (ft * 16 + l15) * 40 + lq * 8);
      *(uint4*)(Bf + ((((size_t)b * 16 + ft) * 64 + kt) * 64 + lane) * 8) = v;
    }
  }
}

// ---------------- k_lse: per (b,i) row: lse = mx + log2(sum 2^(e-mx)); e in log2 domain --------
__global__ __launch_bounds__(256) void k_lse(const uint32_t* __restrict__ adjp,
                                             const float* __restrict__ e_src,
                                             const float* __restrict__ e_dst,
                                             float* __restrict__ lserow) {
  int t = threadIdx.x;
  int lane = t & 63;
  int r = blockIdx.x * 4 + (t >> 6);
  int b = r >> 11, i = r & (N_NODES - 1);
  float es = e_src[r];
  const float* edb = e_dst + ((size_t)b << 11);
  const uint32_t* arow = adjp + (size_t)i * 64;
  float ev[32];
  float mx = -3e38f;
  #pragma unroll
  for (int it = 0; it < 32; ++it) {
    int j = it * 64 + lane;
    float ed = edb[j];
    uint32_t w = arow[j >> 5];
    float s = es + ed;
    float lr = fmaxf(s, 0.01f * s);
    float e = ((w >> (j & 31)) & 1u) ? lr : -1e9f;
    ev[it] = e;
    mx = fmaxf(mx, e);
  }
  #pragma unroll
  for (int m = 1; m <= 32; m <<= 1) mx = fmaxf(mx, __shfl_xor(mx, m));
  float sum = 0.f;
  #pragma unroll
  for (int it = 0; it < 32; ++it) sum += exp2_hw(ev[it] - mx);
  #pragma unroll
  for (int m = 1; m <= 32; m <<= 1) sum += __shfl_xor(sum, m);
  if (lane == 0) lserow[r] = mx + log2_hw(sum);
}

// ---------------- k_pvF6: out = relu(P @ H); 32i x 256f blocks, grid 512 (2 blocks/CU) --------
// b = bid&7 (XCD-pinned), it = bid>>3 (32 rows). 8 waves / 512 thr.
// Producer: wave wv fills A-frag slot (k0l = wv>>1, sub = wv&1) -> ONE computeA per chunk (R=1).
// Consumer: wave wv's ft pair = (wv*2, wv*2+1); per k0: 2 subs x 2 B -> 4 MFMA; 16 MFMA/chunk.
// LDS: Abuf 16KB + sm_ed 8KB + sm_adj 8.3KB = 32.3KB -> 2 blocks/CU, 4 waves/SIMD.
__global__ __launch_bounds__(512) void k_pvF6(const __hip_bfloat16* __restrict__ Bf,
                                              const uint32_t* __restrict__ adjp,
                                              const float* __restrict__ e_src,
                                              const float* __restrict__ e_dst,
                                              const float* __restrict__ lserow,
                                              float* __restrict__ out) {
  __shared__ __align__(16) char Abuf[16384];   // [2 buf][4 k0l][2 sub][64 lane][16B]
  __shared__ float sm_ed[2048];                // 8 KB
  __shared__ uint32_t sm_adj[32 * 65];         // 8.3 KB
  int t = threadIdx.x;
  int b  = blockIdx.x & 7;
  int it = blockIdx.x >> 3;
  int i0 = it * 32;
  int lane = t & 63, wv = t >> 6, l15 = lane & 15, lq = lane >> 4;
  int sub = wv & 1, k0lp = wv >> 1;            // producer slot

  *(f32x4*)(sm_ed + t * 4) = *(const f32x4*)(e_dst + ((size_t)b << 11) + t * 4);
  {
    int row = t >> 4, q = t & 15;              // 32 rows x 16 thr x uint4
    *(uint4*)(sm_adj + row * 65 + q * 4) = *(const uint4*)(adjp + (size_t)(i0 + row) * 64 + q * 4);
  }
  // per-lane row constants for the frag rows this wave produces (rows sub*16 + l15)
  int rg = (b << 11) + i0 + sub * 16 + l15;
  float es = e_src[rg], lse = lserow[rg];
  float esl = es - lse;                 // s_l2 - lse = esl + ed
  float c2  = fmaf(0.01f, es, -lse);    // 0.01*s_l2 - lse = fma(0.01, ed, c2)
  int adjbase = (sub * 16 + l15) * 65;
  int edoff = lq * 8;
  __syncthreads();

  auto computeA = [&](int k0) -> uint4 {
    uint32_t w = sm_adj[adjbase + k0] >> (lq * 8);
    f32x4 e0 = *(const f32x4*)(sm_ed + k0 * 32 + edoff);
    f32x4 e1 = *(const f32x4*)(sm_ed + k0 * 32 + edoff + 4);
    unsigned short u[8];
    #pragma unroll
    for (int e = 0; e < 8; ++e) {
      float ed = (e < 4) ? e0[e] : e1[e - 4];
      float v = fmaxf(esl + ed, fmaf(0.01f, ed, c2));
      float p = exp2_hw(v);
      p = ((w >> e) & 1u) ? p : 0.0f;        // masked: exact 0
      u[e] = bf16r(p);
    }
    uint4 v;
    v.x = (uint32_t)u[0] | ((uint32_t)u[1] << 16);
    v.y = (uint32_t)u[2] | ((uint32_t)u[3] << 16);
    v.z = (uint32_t)u[4] | ((uint32_t)u[5] << 16);
    v.w = (uint32_t)u[6] | ((uint32_t)u[7] << 16);
    return v;
  };

  auto produce = [&](int buf, int ch) {
    uint4 fr = computeA(ch * 4 + k0lp);
    *(uint4*)(Abuf + (((buf * 4 + k0lp) * 2 + sub) << 10) + lane * 16) = fr;
  };

  // B pointers: ft = wv*2 + n
  const __hip_bfloat16* Bp0 = Bf + (((size_t)b * 16 + wv * 2)     * 64) * 512 + (size_t)lane * 8;
  const __hip_bfloat16* Bp1 = Bf + (((size_t)b * 16 + wv * 2 + 1) * 64) * 512 + (size_t)lane * 8;

  f32x4 acc[2][2];
  #pragma unroll
  for (int m = 0; m < 2; ++m)
    #pragma unroll
    for (int n = 0; n < 2; ++n)
      #pragma unroll
      for (int e = 0; e < 4; ++e) acc[m][n][e] = 0.f;

  bf16x8 bA0 = *(const bf16x8*)(Bp0);            // even k0
  bf16x8 bA1 = *(const bf16x8*)(Bp1);
  bf16x8 bB0 = *(const bf16x8*)(Bp0 + 512);      // odd k0
  bf16x8 bB1 = *(const bf16x8*)(Bp1 + 512);

  produce(0, 0);
  __syncthreads();

  for (int ch = 0; ch < 16; ++ch) {
    int buf = ch & 1;
    if (ch < 15) produce(buf ^ 1, ch + 1);
    const char* Ab = Abuf + buf * 8192;
    #pragma unroll
    for (int k0l = 0; k0l < 4; ++k0l) {
      int k0 = ch * 4 + k0l;
      bf16x8 af[2];
      #pragma unroll
      for (int m = 0; m < 2; ++m)
        af[m] = *(const bf16x8*)(Ab + ((k0l * 2 + m) << 10) + lane * 16);
      bf16x8 cb0 = (k0l & 1) ? bB0 : bA0;
      bf16x8 cb1 = (k0l & 1) ? bB1 : bA1;
      if (k0 + 2 < 64) {
        if (k0l & 1) { bB0 = *(const bf16x8*)(Bp0 + (size_t)(k0 + 2) * 512); bB1 = *(const bf16x8*)(Bp1 + (size_t)(k0 + 2) * 512); }
        else         { bA0 = *(const bf16x8*)(Bp0 + (size_t)(k0 + 2) * 512); bA1 = *(const bf16x8*)(Bp1 + (size_t)(k0 + 2) * 512); }
      }
      #pragma unroll
      for (int m = 0; m < 2; ++m) {
        acc[m][0] = __builtin_amdgcn_mfma_f32_16x16x32_bf16(af[m], cb0, acc[m][0], 0, 0, 0);
        acc[m][1] = __builtin_amdgcn_mfma_f32_16x16x32_bf16(af[m], cb1, acc[m][1], 0, 0, 0);
      }
    }
    __syncthreads();
  }

  #pragma unroll
  for (int m = 0; m < 2; ++m)
    #pragma unroll
    for (int n = 0; n < 2; ++n) {
      int col = (wv * 2 + n) * 16 + l15;
      int orow = (b << 11) + i0 + m * 16 + lq * 4;
      #pragma unroll
      for (int r = 0; r < 4; ++r)
        out[(size_t)(orow + r) * FDIM + col] = fmaxf(acc[m][n][r], 0.0f);
    }
}

extern "C" void kernel_launch(void* const* d_in, const int* in_sizes, int n_in,
                              void* d_out, int out_size, void* d_ws, size_t ws_size,
                              hipStream_t stream) {
  const float* inp = (const float*)d_in[0];
  const int*   adj = (const int*)d_in[1];
  const float* W   = (const float*)d_in[2];
  const float* a   = (const float*)d_in[3];
  float* out = (float*)d_out;
  char* ws = (char*)d_ws;

  __hip_bfloat16* Bf   = (__hip_bfloat16*)ws;              //  8,388,608
  float* e_src         = (float*)(ws + 8388608);           //     65,536
  float* e_dst         = (float*)(ws + 8454144);           //     65,536
  float* lserow        = (float*)(ws + 8519680);           //     65,536
  __hip_bfloat16* WT16 = (__hip_bfloat16*)(ws + 8585216);  //    131,072
  float* wa1           = (float*)(ws + 8716288);           //      1,024
  float* wa2           = (float*)(ws + 8717312);           //      1,024
  uint32_t* adjp       = (uint32_t*)(ws + 8718336);        //    524,288 -> end 9,242,624

  k_prep<<<20, 256, 0, stream>>>(W, a, WT16, wa1, wa2);
  k_h2p<<<512, 256, 0, stream>>>(inp, adj, adjp, WT16, wa1, wa2, Bf, e_src, e_dst);
  k_lse<<<4096, 256, 0, stream>>>(adjp, e_src, e_dst, lserow);
  k_pvF6<<<512, 512, 0, stream>>>(Bf, adjp, e_src, e_dst, lserow, out);
}

// Round 18
// 75.178 us; speedup vs baseline: 1.1590x; 1.0150x over previous
//
#include <hip/hip_runtime.h>
#include <hip/hip_bf16.h>
#include <stdint.h>

#define N_NODES 2048
#define FDIM 256
#define LOG2E 1.44269504088896340736f

typedef short bf16x8 __attribute__((ext_vector_type(8)));   // 8 bf16 = 4 VGPRs (MFMA A/B frag)
typedef float f32x4 __attribute__((ext_vector_type(4)));
typedef unsigned short u16x4 __attribute__((ext_vector_type(4)));

static __device__ __forceinline__ unsigned short bf16r(float x) {
  __hip_bfloat16 h = __float2bfloat16(x);
  return __builtin_bit_cast(unsigned short, h);
}

static __device__ __forceinline__ float exp2_hw(float x) { return __builtin_amdgcn_exp2f(x); }
static __device__ __forceinline__ float log2_hw(float x) { return __builtin_amdgcn_logf(x); }

// ---------------- k_prep: WT16 = bf16(W^T); wa1/wa2 = (W@a1/2) * log2(e) --------------------
__global__ __launch_bounds__(256) void k_prep(const float* __restrict__ W, const float* __restrict__ a,
                                              __hip_bfloat16* __restrict__ WT16,
                                              float* __restrict__ wa1, float* __restrict__ wa2) {
  int bid = blockIdx.x, t = threadIdx.x;
  if (bid < 16) {
    __shared__ __hip_bfloat16 T[64][67];
    int k0 = (bid & 3) * 64, f0 = (bid >> 2) * 64;
    int r = t >> 2, c0 = (t & 3) * 16;
    #pragma unroll
    for (int i = 0; i < 4; ++i) {
      f32x4 v = *(const f32x4*)(W + (size_t)(k0 + r) * FDIM + f0 + c0 + i * 4);
      #pragma unroll
      for (int j = 0; j < 4; ++j) T[r][c0 + i * 4 + j] = __float2bfloat16(v[j]);
    }
    __syncthreads();
    int fr = t >> 2, kc = (t & 3) * 16;
    unsigned short buf[16];
    #pragma unroll
    for (int i = 0; i < 16; ++i) buf[i] = __builtin_bit_cast(unsigned short, T[kc + i][fr]);
    uint4* dst = (uint4*)(WT16 + (size_t)(f0 + fr) * FDIM + k0 + kc);
    dst[0] = *(uint4*)&buf[0];
    dst[1] = *(uint4*)&buf[8];
  } else {
    int k = (bid - 16) * 64 + (t >> 2), q = t & 3;
    float s1 = 0.f, s2 = 0.f;
    #pragma unroll
    for (int i = 0; i < 16; ++i) {
      int f = q * 64 + i * 4;
      f32x4 w  = *(const f32x4*)(W + (size_t)k * FDIM + f);
      f32x4 v1 = *(const f32x4*)(a + f);
      f32x4 v2 = *(const f32x4*)(a + FDIM + f);
      #pragma unroll
      for (int j = 0; j < 4; ++j) { s1 += w[j] * v1[j]; s2 += w[j] * v2[j]; }
    }
    s1 += __shfl_xor(s1, 1); s1 += __shfl_xor(s1, 2);
    s2 += __shfl_xor(s2, 1); s2 += __shfl_xor(s2, 2);
    if (q == 0) { wa1[k] = s1 * LOG2E; wa2[k] = s2 * LOG2E; }
  }
}

// ---------------- k_h2p: adj-pack prologue + h = inp@W via MFMA -> Bf + e_src/e_dst ------------
// Bf[b][ft(16)][k0(64)][lane(64)][e(8)]: lane holds h[k = k0*32+(lane>>4)*8+e][f = ft*16+(lane&15)]
__global__ __launch_bounds__(256) void k_h2p(const float* __restrict__ inp,
                                             const int* __restrict__ adj, uint32_t* __restrict__ adjp,
                                             const __hip_bfloat16* __restrict__ WT16,
                                             const float* __restrict__ wa1, const float* __restrict__ wa2,
                                             __hip_bfloat16* __restrict__ Bf,
                                             float* __restrict__ e_src, float* __restrict__ e_dst) {
  __shared__ char lds_raw[20480];
  __hip_bfloat16* Asm = (__hip_bfloat16*)lds_raw;  // [32][264] bf16
  int t = threadIdx.x;
  int r0 = blockIdx.x * 32;
  int b = r0 >> 11, j0 = r0 & (N_NODES - 1);

  {  // ---- adj pack: rows bid*4 .. +4
    int prow = blockIdx.x * 4 + (t >> 6);
    int lane = t & 63;
    const int* row = adj + (size_t)prow * N_NODES;
    #pragma unroll
    for (int it = 0; it < 32; ++it) {
      int v = row[it * 64 + lane];
      unsigned long long m = __ballot(v != 0);
      if (lane == 0) {
        adjp[prow * 64 + it * 2]     = (uint32_t)(m & 0xffffffffull);
        adjp[prow * 64 + it * 2 + 1] = (uint32_t)(m >> 32);
      }
    }
  }

  {
    int r = t >> 3, q = t & 7, c0 = q * 32;
    const float* ip = inp + (size_t)(r0 + r) * FDIM + c0;
    float s1 = 0.f, s2 = 0.f;
    #pragma unroll
    for (int i = 0; i < 8; ++i) {
      f32x4 v  = *(const f32x4*)(ip + i * 4);
      f32x4 u1 = *(const f32x4*)(wa1 + c0 + i * 4);
      f32x4 u2 = *(const f32x4*)(wa2 + c0 + i * 4);
      u16x4 pk;
      #pragma unroll
      for (int j = 0; j < 4; ++j) {
        s1 += v[j] * u1[j];
        s2 += v[j] * u2[j];
        pk[j] = bf16r(v[j]);
      }
      *(u16x4*)(Asm + r * 264 + c0 + i * 4) = pk;
    }
    s1 += __shfl_xor(s1, 1); s1 += __shfl_xor(s1, 2); s1 += __shfl_xor(s1, 4);
    s2 += __shfl_xor(s2, 1); s2 += __shfl_xor(s2, 2); s2 += __shfl_xor(s2, 4);
    if (q == 0) { e_src[r0 + r] = s1; e_dst[r0 + r] = s2; }
  }
  __syncthreads();

  int lane = t & 63, wv = t >> 6, l15 = lane & 15, lq = lane >> 4;
  int f0 = wv * 64;
  f32x4 acc[2][4];
  #pragma unroll
  for (int mf = 0; mf < 2; ++mf)
    #pragma unroll
    for (int nf = 0; nf < 4; ++nf)
      #pragma unroll
      for (int e = 0; e < 4; ++e) acc[mf][nf][e] = 0.f;

  #pragma unroll
  for (int ks = 0; ks < 8; ++ks) {
    int k0 = ks * 32;
    bf16x8 af[2], bfr[4];
    #pragma unroll
    for (int mf = 0; mf < 2; ++mf)
      af[mf] = *(const bf16x8*)(Asm + (mf * 16 + l15) * 264 + k0 + lq * 8);
    #pragma unroll
    for (int nf = 0; nf < 4; ++nf)
      bfr[nf] = *(const bf16x8*)(WT16 + (size_t)(f0 + nf * 16 + l15) * FDIM + k0 + lq * 8);
    #pragma unroll
    for (int mf = 0; mf < 2; ++mf)
      #pragma unroll
      for (int nf = 0; nf < 4; ++nf)
        acc[mf][nf] = __builtin_amdgcn_mfma_f32_16x16x32_bf16(af[mf], bfr[nf], acc[mf][nf], 0, 0, 0);
  }

  __syncthreads();
  __hip_bfloat16* Tsm = (__hip_bfloat16*)lds_raw;  // [256][40] bf16: Tsm[f][j_local]
  #pragma unroll
  for (int mf = 0; mf < 2; ++mf)
    #pragma unroll
    for (int nf = 0; nf < 4; ++nf) {
      u16x4 pk;
      #pragma unroll
      for (int r = 0; r < 4; ++r) pk[r] = bf16r(acc[mf][nf][r]);
      int fl = f0 + nf * 16 + l15;
      int jl = mf * 16 + lq * 4;
      *(u16x4*)(Tsm + fl * 40 + jl) = pk;
    }
  __syncthreads();
  {
    int kt = j0 >> 5;                    // this block covers exactly one k0-block
    #pragma unroll
    for (int q = 0; q < 4; ++q) {
      int ft = (t >> 6) * 4 + q;
      uint4 v = *(const uint4*)(Tsm + (ft * 16 + l15) * 40 + lq * 8);
      *(uint4*)(Bf + ((((size_t)b * 16 + ft) * 64 + kt) * 64 + lane) * 8) = v;
    }
  }
}

// ---------------- k_lse: per (b,i) row: lse = mx + log2(sum 2^(e-mx)); e in log2 domain --------
__global__ __launch_bounds__(256) void k_lse(const uint32_t* __restrict__ adjp,
                                             const float* __restrict__ e_src,
                                             const float* __restrict__ e_dst,
                                             float* __restrict__ lserow) {
  int t = threadIdx.x;
  int lane = t & 63;
  int r = blockIdx.x * 4 + (t >> 6);
  int b = r >> 11, i = r & (N_NODES - 1);
  float es = e_src[r];
  const float* edb = e_dst + ((size_t)b << 11);
  const uint32_t* arow = adjp + (size_t)i * 64;
  float ev[32];
  float mx = -3e38f;
  #pragma unroll
  for (int it = 0; it < 32; ++it) {
    int j = it * 64 + lane;
    float ed = edb[j];
    uint32_t w = arow[j >> 5];
    float s = es + ed;
    float lr = fmaxf(s, 0.01f * s);
    float e = ((w >> (j & 31)) & 1u) ? lr : -1e9f;
    ev[it] = e;
    mx = fmaxf(mx, e);
  }
  #pragma unroll
  for (int m = 1; m <= 32; m <<= 1) mx = fmaxf(mx, __shfl_xor(mx, m));
  float sum = 0.f;
  #pragma unroll
  for (int it = 0; it < 32; ++it) sum += exp2_hw(ev[it] - mx);
  #pragma unroll
  for (int m = 1; m <= 32; m <<= 1) sum += __shfl_xor(sum, m);
  if (lane == 0) lserow[r] = mx + log2_hw(sum);
}

// ---------------- k_pvF7: out = relu(P @ H); 64i x 256f, 1024 thr / 16 waves, grid 256 --------
// b = bid&7 (XCD-pinned), it = bid>>3 (64 rows). Halves chip-wide B L2 traffic vs 32i blocks.
// Producer: wave wv fills slot (k0l = wv>>2, sub = wv&3) -> ONE computeA per chunk (R=1).
// Consumer: wave wv owns ft = wv; per k0: 4 subs x 1 B -> 4 MFMA; 16 MFMA per 4-k0 chunk.
// LDS: Abuf 32KB + sm_ed 8KB + sm_adj 16.6KB = 56.6KB < 64KB static limit (R12 lesson).
__global__ __launch_bounds__(1024) void k_pvF7(const __hip_bfloat16* __restrict__ Bf,
                                               const uint32_t* __restrict__ adjp,
                                               const float* __restrict__ e_src,
                                               const float* __restrict__ e_dst,
                                               const float* __restrict__ lserow,
                                               float* __restrict__ out) {
  __shared__ __align__(16) char Abuf[32768];   // [2 buf][4 k0l][4 sub][64 lane][16B]
  __shared__ float sm_ed[2048];                // 8 KB
  __shared__ uint32_t sm_adj[64 * 65];         // 16.6 KB
  int t = threadIdx.x;
  int b  = blockIdx.x & 7;
  int it = blockIdx.x >> 3;
  int i0 = it * 64;
  int lane = t & 63, wv = t >> 6, l15 = lane & 15, lq = lane >> 4;
  int sub = wv & 3, k0lp = wv >> 2;            // producer slot

  {  // stage e_dst row (2048 f32): 1024 thr x 2 floats
    *(float2*)(sm_ed + t * 2) = *(const float2*)(e_dst + ((size_t)b << 11) + t * 2);
  }
  {  // stage adjp rows i0..i0+64: 1024 thr x uint4
    int row = t >> 4, q = t & 15;
    *(uint4*)(sm_adj + row * 65 + q * 4) = *(const uint4*)(adjp + (size_t)(i0 + row) * 64 + q * 4);
  }
  // per-lane row constants for the frag rows this wave produces (rows sub*16 + l15)
  int rg = (b << 11) + i0 + sub * 16 + l15;
  float es = e_src[rg], lse = lserow[rg];
  float esl = es - lse;                 // s_l2 - lse = esl + ed
  float c2  = fmaf(0.01f, es, -lse);    // 0.01*s_l2 - lse = fma(0.01, ed, c2)
  int adjbase = (sub * 16 + l15) * 65;
  int edoff = lq * 8;
  __syncthreads();

  auto computeA = [&](int k0) -> uint4 {
    uint32_t w = sm_adj[adjbase + k0] >> (lq * 8);
    f32x4 e0 = *(const f32x4*)(sm_ed + k0 * 32 + edoff);
    f32x4 e1 = *(const f32x4*)(sm_ed + k0 * 32 + edoff + 4);
    unsigned short u[8];
    #pragma unroll
    for (int e = 0; e < 8; ++e) {
      float ed = (e < 4) ? e0[e] : e1[e - 4];
      float v = fmaxf(esl + ed, fmaf(0.01f, ed, c2));
      float p = exp2_hw(v);
      p = ((w >> e) & 1u) ? p : 0.0f;        // masked: exact 0
      u[e] = bf16r(p);
    }
    uint4 v;
    v.x = (uint32_t)u[0] | ((uint32_t)u[1] << 16);
    v.y = (uint32_t)u[2] | ((uint32_t)u[3] << 16);
    v.z = (uint32_t)u[4] | ((uint32_t)u[5] << 16);
    v.w = (uint32_t)u[6] | ((uint32_t)u[7] << 16);
    return v;
  };

  auto produce = [&](int buf, int ch) {
    uint4 fr = computeA(ch * 4 + k0lp);
    *(uint4*)(Abuf + (((buf * 4 + k0lp) * 4 + sub) << 10) + lane * 16) = fr;
  };

  // B pointer: ft = wv
  const __hip_bfloat16* Bp = Bf + (((size_t)b * 16 + wv) * 64) * 512 + (size_t)lane * 8;

  f32x4 acc[4];
  #pragma unroll
  for (int m = 0; m < 4; ++m)
    #pragma unroll
    for (int e = 0; e < 4; ++e) acc[m][e] = 0.f;

  bf16x8 bA = *(const bf16x8*)(Bp);            // even k0
  bf16x8 bB = *(const bf16x8*)(Bp + 512);      // odd k0

  produce(0, 0);
  __syncthreads();

  for (int ch = 0; ch < 16; ++ch) {
    int buf = ch & 1;
    if (ch < 15) produce(buf ^ 1, ch + 1);
    const char* Ab = Abuf + buf * 16384;
    #pragma unroll
    for (int k0l = 0; k0l < 4; ++k0l) {
      int k0 = ch * 4 + k0l;
      bf16x8 af[4];
      #pragma unroll
      for (int m = 0; m < 4; ++m)
        af[m] = *(const bf16x8*)(Ab + ((k0l * 4 + m) << 10) + lane * 16);
      bf16x8 cb = (k0l & 1) ? bB : bA;
      if (k0 + 2 < 64) {
        if (k0l & 1) bB = *(const bf16x8*)(Bp + (size_t)(k0 + 2) * 512);
        else         bA = *(const bf16x8*)(Bp + (size_t)(k0 + 2) * 512);
      }
      #pragma unroll
      for (int m = 0; m < 4; ++m)
        acc[m] = __builtin_amdgcn_mfma_f32_16x16x32_bf16(af[m], cb, acc[m], 0, 0, 0);
    }
    __syncthreads();
  }

  #pragma unroll
  for (int m = 0; m < 4; ++m) {
    int col = wv * 16 + l15;
    int orow = (b << 11) + i0 + m * 16 + lq * 4;
    #pragma unroll
    for (int r = 0; r < 4; ++r)
      out[(size_t)(orow + r) * FDIM + col] = fmaxf(acc[m][r], 0.0f);
  }
}

extern "C" void kernel_launch(void* const* d_in, const int* in_sizes, int n_in,
                              void* d_out, int out_size, void* d_ws, size_t ws_size,
                              hipStream_t stream) {
  const float* inp = (const float*)d_in[0];
  const int*   adj = (const int*)d_in[1];
  const float* W   = (const float*)d_in[2];
  const float* a   = (const float*)d_in[3];
  float* out = (float*)d_out;
  char* ws = (char*)d_ws;

  __hip_bfloat16* Bf   = (__hip_bfloat16*)ws;              //  8,388,608
  float* e_src         = (float*)(ws + 8388608);           //     65,536
  float* e_dst         = (float*)(ws + 8454144);           //     65,536
  float* lserow        = (float*)(ws + 8519680);           //     65,536
  __hip_bfloat16* WT16 = (__hip_bfloat16*)(ws + 8585216);  //    131,072
  float* wa1           = (float*)(ws + 8716288);           //      1,024
  float* wa2           = (float*)(ws + 8717312);           //      1,024
  uint32_t* adjp       = (uint32_t*)(ws + 8718336);        //    524,288 -> end 9,242,624

  k_prep<<<20, 256, 0, stream>>>(W, a, WT16, wa1, wa2);
  k_h2p<<<512, 256, 0, stream>>>(inp, adj, adjp, WT16, wa1, wa2, Bf, e_src, e_dst);
  k_lse<<<4096, 256, 0, stream>>>(adjp, e_src, e_dst, lserow);
  k_pvF7<<<256, 1024, 0, stream>>>(Bf, adjp, e_src, e_dst, lserow, out);
}